// Round 11
// baseline (961.579 us; speedup 1.0000x reference)
//
#include <hip/hip_runtime.h>

// B=1024, H=56, J=64, N=56, I=64.
// t4[b,i,m,n] = sum_{k,j} x[b, m+k-1, j, n] * W2[i,k,j]   (zero-padded in h)
// y[b,i,m,(n+1)%56] = t4[b,i,m,n]*W1[i,0] + t4[b,i,(m-1)%56,n]*W1[i,1]
//
// Folded 4-tap: y[i,m,c] = sum_{k'} W2'[i,k',j] * x[m-2+k', j, (c-1)%56]
//   W2' = [bW0, aW0+bW1, aW1+bW2, aW2] (boundary taps skipped);
//   m=0 wrap: W2'' = [bW0, bW1, aW1, aW2] over x54,x55,x0,x1.
//
// DIRECT-LOAD structure (no LDS, no barriers): x's natural [j][n] layout IS
// the MFMA B-operand orientation. Per slice h each lane loads its fragment
// elements straight from global (8 dwords per fragment, 64B-coalesced per
// 16-lane group), converts in-register, and feeds the rolling accumulators
// (slice h -> rows m=h-1..h+2, k'=h-m+2). Each wave is a fully independent
// load/MFMA/store stream; 4 i-tile waves per block read identical x
// addresses (L1 broadcast). n-roll folded into per-lane source column.

#define HXW 3584   // 64*56 floats per h-slice

typedef __attribute__((ext_vector_type(8))) short short8_t;
typedef __attribute__((ext_vector_type(4))) float f32x4;

__device__ __forceinline__ unsigned short f2bf(float f) {
  union { float f; unsigned u; } v; v.f = f;
  return (unsigned short)((v.u + 0x7FFFu + ((v.u >> 16) & 1u)) >> 16);
}

// ---- pre-kernel: merged 4-tap weight sets (bf16) into ws ----
__global__ void prep_weights(const float* __restrict__ W1,
                             const float* __restrict__ W2,
                             unsigned short* __restrict__ wp) {
  const int t = threadIdx.x;            // 256 threads
  const int i = t >> 2;
  const int j0 = (t & 3) * 16;
  const float a = W1[i * 2 + 0], b = W1[i * 2 + 1];
  const float* w = W2 + i * 192;
  unsigned short* p0 = wp + i * 256;            // W2'  (rolling)
  unsigned short* p1 = wp + 16384 + i * 256;    // W2'' (m = 0 wrap)
  for (int j = j0; j < j0 + 16; ++j) {
    const float w0 = w[j], w1 = w[64 + j], w2 = w[128 + j];
    p0[j]       = f2bf(b * w0);
    p0[64 + j]  = f2bf(a * w0 + b * w1);
    p0[128 + j] = f2bf(a * w1 + b * w2);
    p0[192 + j] = f2bf(a * w2);
    p1[j]       = f2bf(b * w0);
    p1[64 + j]  = f2bf(b * w1);
    p1[128 + j] = f2bf(a * w1);
    p1[192 + j] = f2bf(a * w2);
  }
}

__global__ __launch_bounds__(256, 4) void conv_direct(
    const float* __restrict__ x, const unsigned short* __restrict__ wp,
    float* __restrict__ out) {
  const int tid = threadIdx.x;
  const int iw  = tid >> 6;           // wave = i-tile (0..3)
  const int lq  = tid & 15;
  const int lg  = (tid >> 4) & 3;

  const int bid   = blockIdx.x;
  const int batch = bid >> 2;
  const int ct    = bid & 3;          // col tile: out cols 16*ct + lq

  const float* __restrict__ xb = x + (size_t)batch * 200704;  // 56*64*56

  // ---- A fragments: W2' (64 x 256 bf16), i = 16*iw + lq ----
  short8_t af[8];
  const unsigned short* ap = wp + ((16 * iw + lq) << 8) + lg * 8;
  #pragma unroll
  for (int s = 0; s < 8; ++s) af[s] = *(const short8_t*)(ap + s * 32);
  const unsigned short* wpp = wp + 16384 + ((16 * iw + lq) << 8) + lg * 8;

  // ---- per-lane source pointer: src col (cout+55)%56, j base 8*lg ----
  const int cout = 16 * ct + lq;
  const int csrc = (cout + 55) % 56;
  const float* const xcol = xb + csrc + (size_t)(8 * lg) * 56;

  float* const outp = out + ((size_t)batch * 64 + 16 * iw + 4 * lg) * 3136 + cout;
  const bool act = cout < 56;

  float Xa[16], Xb[16];
  short8_t f0, f1;

  // issue 16 dword loads for slice h (fragment elements, 64B-coalesced)
  auto loadS = [&](int h, float* X) {
    const float* p = xcol + (size_t)h * HXW;
    #pragma unroll
    for (int half = 0; half < 2; ++half)
      #pragma unroll
      for (int e = 0; e < 8; ++e)
        X[half * 8 + e] = p[(32 * half + e) * 56];
  };

  // fp32 -> bf16 fragments (packed bit-arithmetic, rne)
  auto mkfrag = [&](const float* X) {
    union { unsigned u[4]; short8_t s; } u0, u1;
    #pragma unroll
    for (int pq = 0; pq < 4; ++pq) {
      u0.u[pq] = (unsigned)f2bf(X[2 * pq]) | ((unsigned)f2bf(X[2 * pq + 1]) << 16);
      u1.u[pq] = (unsigned)f2bf(X[8 + 2 * pq]) | ((unsigned)f2bf(X[9 + 2 * pq]) << 16);
    }
    f0 = u0.s; f1 = u1.s;
  };

  auto tap2 = [&](f32x4& a, int kp) {
    a = __builtin_amdgcn_mfma_f32_16x16x32_bf16(af[2 * kp], f0, a, 0, 0, 0);
    a = __builtin_amdgcn_mfma_f32_16x16x32_bf16(af[2 * kp + 1], f1, a, 0, 0, 0);
  };
  auto tapW = [&](f32x4& a, int kpp) {   // W'' tap pair for the m=0 wrap
    const short8_t w0 = *(const short8_t*)(wpp + kpp * 64);
    const short8_t w1 = *(const short8_t*)(wpp + kpp * 64 + 32);
    a = __builtin_amdgcn_mfma_f32_16x16x32_bf16(w0, f0, a, 0, 0, 0);
    a = __builtin_amdgcn_mfma_f32_16x16x32_bf16(w1, f1, a, 0, 0, 0);
  };
  auto storeRow = [&](int m, const f32x4& a) {
    if (act) {
      float* pm = outp + m * 56;
      #pragma unroll
      for (int r = 0; r < 4; ++r) pm[(size_t)r * 3136] = a[r];
    }
  };

  f32x4 acc[4], m0acc;
  #pragma unroll
  for (int s = 0; s < 4; ++s) acc[s] = (f32x4){0.f, 0.f, 0.f, 0.f};
  m0acc = (f32x4){0.f, 0.f, 0.f, 0.f};

  // ---- prologue: prime depth-2 register pipeline ----
  loadS(0, Xa);
  loadS(1, Xb);

  // h=0: rows m=2(k'0), 1(k'1); wrap tap k''=2 (x0)
  mkfrag(Xa); loadS(2, Xa);
  tap2(acc[2], 0); tap2(acc[1], 1); tapW(m0acc, 2);
  // h=1: rows 3(k'0), 2(k'1), 1(k'2); wrap tap k''=3 (x1)
  mkfrag(Xb); loadS(3, Xb);
  tap2(acc[3], 0); tap2(acc[2], 1); tap2(acc[1], 2); tapW(m0acc, 3);

  // step h: consume buf, reload slice h+2 into same buf; taps m=h+2..h-1
  // (k'=0..3); store row h-1 and reset its accumulator.
#define STEP(H, BUF)                                                        \
  do {                                                                      \
    mkfrag(BUF); loadS((H) + 2, BUF);                                       \
    tap2(acc[((H) + 2) & 3], 0);                                            \
    tap2(acc[((H) + 1) & 3], 1);                                            \
    tap2(acc[(H) & 3], 2);                                                  \
    tap2(acc[((H) + 3) & 3], 3);                                            \
    storeRow((H) - 1, acc[((H) + 3) & 3]);                                  \
    acc[((H) + 3) & 3] = (f32x4){0.f, 0.f, 0.f, 0.f};                       \
  } while (0)

  // ---- main: h = 2..53, 13 iters x 4 (buffers/acc indices all static) ----
  #pragma unroll 1
  for (int u = 0; u < 13; ++u) {
    const int h = 2 + 4 * u;
    STEP(h + 0, Xa);
    STEP(h + 1, Xb);
    STEP(h + 2, Xa);
    STEP(h + 3, Xb);
  }
#undef STEP

  // ---- tail: h=54 (Xa), h=55 (Xb) ----
  mkfrag(Xa);
  tap2(acc[3], 1); tap2(acc[2], 2); tap2(acc[1], 3); tapW(m0acc, 0);
  storeRow(53, acc[1]);
  mkfrag(Xb);
  tap2(acc[3], 2); tap2(acc[2], 3); tapW(m0acc, 1);
  storeRow(54, acc[2]);
  storeRow(55, acc[3]);
  storeRow(0, m0acc);
}

extern "C" void kernel_launch(void* const* d_in, const int* in_sizes, int n_in,
                              void* d_out, int out_size, void* d_ws, size_t ws_size,
                              hipStream_t stream) {
  const float* x  = (const float*)d_in[0];
  const float* W1 = (const float*)d_in[1];
  const float* W2 = (const float*)d_in[2];
  float* out = (float*)d_out;
  unsigned short* wp = (unsigned short*)d_ws;
  prep_weights<<<1, 256, 0, stream>>>(W1, W2, wp);
  conv_direct<<<4096, 256, 0, stream>>>(x, wp, out);
}

// Round 12
// 528.743 us; speedup vs baseline: 1.8186x; 1.8186x over previous
//
#include <hip/hip_runtime.h>

// B=1024, H=56, J=64, N=56, I=64.
// Folded 4-tap: y[i,m,c] = sum_{k'} W2'[i,k',j] * x[m-2+k', j, (c-1)%56]
//   W2' = [bW0, aW0+bW1, aW1+bW2, aW2] (boundary taps skipped);
//   m=0 wrap: W2'' = [bW0, bW1, aW1, aW2] over x54,x55,x0,x1.
// Rolling: slice h feeds rows m=h-1..h+2 (k'=h-m+2); 2 slices per barrier
// phase (28 phases). LDS: 4 slots x [56 n-rows][76 ushort] bf16 transposed,
// ROW STRIDE 152B (38 dw) -> staging writes ~3-way (vs 7-way at 16B-aligned
// strides), frag reads 2x ds_read_b64 per half at ~2-way (free).
// n-roll via rotated rows (col c reads row (c+55)%56) -> aligned stores.
// Grid 4096 = batch x i-quarter, XCD-grouped so 4 siblings share x via L2.

#define ROWU 76              // ushorts per n-row (152 B)
#define SLOTU (56 * ROWU)    // 4256 ushorts per slice slot

typedef __attribute__((ext_vector_type(8))) short short8_t;
typedef __attribute__((ext_vector_type(4))) short short4_t;
typedef __attribute__((ext_vector_type(4))) float f32x4;

__device__ __forceinline__ unsigned short f2bf(float f) {
  union { float f; unsigned u; } v; v.f = f;
  return (unsigned short)((v.u + 0x7FFFu + ((v.u >> 16) & 1u)) >> 16);
}

#define BARRIER() do {                                   \
    asm volatile("s_waitcnt lgkmcnt(0)" ::: "memory");   \
    __builtin_amdgcn_s_barrier();                        \
  } while (0)

// ---- pre-kernel: merged 4-tap weight sets (bf16) into ws ----
__global__ void prep_weights(const float* __restrict__ W1,
                             const float* __restrict__ W2,
                             unsigned short* __restrict__ wp) {
  const int t = threadIdx.x;            // 256 threads
  const int i = t >> 2;
  const int j0 = (t & 3) * 16;
  const float a = W1[i * 2 + 0], b = W1[i * 2 + 1];
  const float* w = W2 + i * 192;
  unsigned short* p0 = wp + i * 256;            // W2'  (rolling)
  unsigned short* p1 = wp + 16384 + i * 256;    // W2'' (m = 0 wrap)
  for (int j = j0; j < j0 + 16; ++j) {
    const float w0 = w[j], w1 = w[64 + j], w2 = w[128 + j];
    p0[j]       = f2bf(b * w0);
    p0[64 + j]  = f2bf(a * w0 + b * w1);
    p0[128 + j] = f2bf(a * w1 + b * w2);
    p0[192 + j] = f2bf(a * w2);
    p1[j]       = f2bf(b * w0);
    p1[64 + j]  = f2bf(b * w1);
    p1[128 + j] = f2bf(a * w1);
    p1[192 + j] = f2bf(a * w2);
  }
}

__global__ __launch_bounds__(256, 2) void conv2s(
    const float* __restrict__ x, const unsigned short* __restrict__ wp,
    float* __restrict__ out) {
  __shared__ unsigned short lds[4 * SLOTU];   // 34048 B -> 4 blocks/CU

  const int tid = threadIdx.x;
  const int ct  = tid >> 6;           // wave = col tile
  const int lq  = tid & 15;
  const int lg  = (tid >> 4) & 3;

  // XCD-grouped bijective swizzle: 4 iq-siblings of a batch on one XCD
  const int bid = blockIdx.x;
  const int r = bid >> 3;
  const int batch = (bid & 7) * 128 + (r >> 2);
  const int iq = r & 3;

  const float* __restrict__ xb = x + (size_t)batch * 200704;

  // ---- A fragments: W2' (64 x 256 bf16), i = 16*iq + lq ----
  short8_t af[8];
  const unsigned short* ap = wp + ((16 * iq + lq) << 8) + lg * 8;
  #pragma unroll
  for (int s = 0; s < 8; ++s) af[s] = *(const short8_t*)(ap + s * 32);
  const unsigned short* wpp = wp + 16384 + ((16 * iq + lq) << 8) + lg * 8;

  // ---- B read base: col c = 16*ct + lq reads rotated row (c+55)%56 ----
  const int c = 16 * ct + lq;
  const int rbase = ((c + 55) % 56) * ROWU + 8 * lg;   // + slot*SLOTU + 32*half
  const bool act = c < 56;

  float* const outp = out + ((size_t)batch * 64 + 16 * iq + 4 * lg) * 3136 + c;

  // ---- staging: 224 workers = j-quad(16) x n-quad(14) ----
  const bool stg = tid < 224;
  const int j4 = tid / 14, n4 = tid % 14;
  const float* const xsrc = xb + (size_t)(4 * j4) * 56 + 4 * n4;
  unsigned short* const wb0 = &lds[(size_t)(4 * n4) * ROWU + 4 * j4];

  float4 Ra[4], Rb[4];
  auto issue = [&](int h, float4* R) {
    if (stg && h < 56) {
      const float* p = xsrc + (size_t)h * 3584;
      R[0] = *(const float4*)(p);
      R[1] = *(const float4*)(p + 56);
      R[2] = *(const float4*)(p + 112);
      R[3] = *(const float4*)(p + 168);
    }
  };
  auto putS = [&](int slot, const float4* R) {   // rows 4n4+q get j 4j4..+3
    if (stg) {
      unsigned short* wb = wb0 + slot * SLOTU;
      short4_t v;
      v[0] = (short)f2bf(R[0].x); v[1] = (short)f2bf(R[1].x);
      v[2] = (short)f2bf(R[2].x); v[3] = (short)f2bf(R[3].x);
      *(short4_t*)(wb) = v;
      v[0] = (short)f2bf(R[0].y); v[1] = (short)f2bf(R[1].y);
      v[2] = (short)f2bf(R[2].y); v[3] = (short)f2bf(R[3].y);
      *(short4_t*)(wb + ROWU) = v;
      v[0] = (short)f2bf(R[0].z); v[1] = (short)f2bf(R[1].z);
      v[2] = (short)f2bf(R[2].z); v[3] = (short)f2bf(R[3].z);
      *(short4_t*)(wb + 2 * ROWU) = v;
      v[0] = (short)f2bf(R[0].w); v[1] = (short)f2bf(R[1].w);
      v[2] = (short)f2bf(R[2].w); v[3] = (short)f2bf(R[3].w);
      *(short4_t*)(wb + 3 * ROWU) = v;
    }
  };

  f32x4 acc[4], m0acc;
  #pragma unroll
  for (int s = 0; s < 4; ++s) acc[s] = (f32x4){0.f, 0.f, 0.f, 0.f};
  m0acc = (f32x4){0.f, 0.f, 0.f, 0.f};
  short8_t fr0, fr1;

  auto RF = [&](int slot) {   // frag: 2 halves x 2 ds_read_b64
    const unsigned short* rp = &lds[slot * SLOTU + rbase];
    short4_t a0 = *(const short4_t*)(rp);
    short4_t a1 = *(const short4_t*)(rp + 4);
    short4_t b0 = *(const short4_t*)(rp + 32);
    short4_t b1 = *(const short4_t*)(rp + 36);
    fr0 = __builtin_shufflevector(a0, a1, 0, 1, 2, 3, 4, 5, 6, 7);
    fr1 = __builtin_shufflevector(b0, b1, 0, 1, 2, 3, 4, 5, 6, 7);
  };
  auto TAP = [&](f32x4& A, int K) {
    A = __builtin_amdgcn_mfma_f32_16x16x32_bf16(af[2 * K], fr0, A, 0, 0, 0);
    A = __builtin_amdgcn_mfma_f32_16x16x32_bf16(af[2 * K + 1], fr1, A, 0, 0, 0);
  };
  auto TAPW = [&](int KP) {
    const short8_t w0 = *(const short8_t*)(wpp + KP * 64);
    const short8_t w1 = *(const short8_t*)(wpp + KP * 64 + 32);
    m0acc = __builtin_amdgcn_mfma_f32_16x16x32_bf16(w0, fr0, m0acc, 0, 0, 0);
    m0acc = __builtin_amdgcn_mfma_f32_16x16x32_bf16(w1, fr1, m0acc, 0, 0, 0);
  };
  auto ST = [&](int m, const f32x4& A) {
    if (act) {
      float* pm = outp + m * 56;
      #pragma unroll
      for (int rr = 0; rr < 4; ++rr) pm[(size_t)rr * 3136] = A[rr];
    }
  };

  // ---- prologue: stage slices 0,1; prime depth-2 ----
  issue(0, Ra); issue(1, Rb);
  putS(0, Ra);  putS(1, Rb);
  BARRIER();
  issue(2, Ra); issue(3, Rb);

  // phase 0 (h=0,1): boundary taps + wrap
  RF(0);
  TAP(acc[2], 0); TAP(acc[1], 1); TAPW(2);
  RF(1);
  TAP(acc[3], 0); TAP(acc[2], 1); TAP(acc[1], 2); TAPW(3);
  putS(2, Ra); issue(4, Ra);
  putS(3, Rb); issue(5, Rb);
  BARRIER();

  // full phase: slices H, H+1 (H even); slots/acc fold to literals
#define PH(H) do {                                                       \
    RF((H) & 3);                                                         \
    TAP(acc[((H) + 2) & 3], 0); TAP(acc[((H) + 1) & 3], 1);              \
    TAP(acc[(H) & 3], 2);       TAP(acc[((H) + 3) & 3], 3);              \
    ST((H) - 1, acc[((H) + 3) & 3]);                                     \
    acc[((H) + 3) & 3] = (f32x4){0.f, 0.f, 0.f, 0.f};                    \
    RF(((H) + 1) & 3);                                                   \
    TAP(acc[((H) + 3) & 3], 0); TAP(acc[((H) + 2) & 3], 1);              \
    TAP(acc[((H) + 1) & 3], 2); TAP(acc[(H) & 3], 3);                    \
    ST((H), acc[(H) & 3]);                                               \
    acc[(H) & 3] = (f32x4){0.f, 0.f, 0.f, 0.f};                          \
    putS(((H) + 2) & 3, Ra); issue((H) + 4, Ra);                         \
    putS(((H) + 3) & 3, Rb); issue((H) + 5, Rb);                         \
    BARRIER();                                                           \
  } while (0)

  PH(2);
  #pragma unroll 1
  for (int u = 0; u < 12; ++u) {
    const int H0 = 4 * u + 4;
    PH(H0);          // H0 & 3 == 0: folds
    PH(H0 + 2);      // (H0+2) & 3 == 2: folds
  }
  PH(52);            // stages 54,55; issues 56,57 skipped
#undef PH

  // final phase (h=54,55): slots 2,3
  RF(2);
  TAP(acc[3], 1); TAP(acc[2], 2); TAP(acc[1], 3); TAPW(0);
  ST(53, acc[1]);
  RF(3);
  TAP(acc[3], 2); TAP(acc[2], 3); TAPW(1);
  ST(54, acc[2]); ST(55, acc[3]); ST(0, m0acc);
}

extern "C" void kernel_launch(void* const* d_in, const int* in_sizes, int n_in,
                              void* d_out, int out_size, void* d_ws, size_t ws_size,
                              hipStream_t stream) {
  const float* x  = (const float*)d_in[0];
  const float* W1 = (const float*)d_in[1];
  const float* W2 = (const float*)d_in[2];
  float* out = (float*)d_out;
  unsigned short* wp = (unsigned short*)d_ws;
  prep_weights<<<1, 256, 0, stream>>>(W1, W2, wp);
  conv2s<<<4096, 256, 0, stream>>>(x, wp, out);
}